// Round 13
// baseline (169.454 us; speedup 1.0000x reference)
//
#include <hip/hip_runtime.h>
#include <hip/hip_fp16.h>

#define BB 4
#define CC 32
#define HH 480
#define WW 640
#define HWv (HH*WW)

union H8 { __half h[8]; float4 f4; };
union H4 { short4 s; __half h[4]; };

// ---------------------------------------------------------------------------
// Kernel 1: 3x3 conv (32->8) + bias + affinity normalization, fused.
// Exact R9 structure (best measured conv: 108 us). K stored fp16.
// Output: K [B][9][H][W] fp16, K[0] = 1 - sum(a), K[1..8] = aff_k / sum|aff|
// ---------------------------------------------------------------------------
__global__ __launch_bounds__(128) void conv_gen(const float* __restrict__ kx,
                                                const float* __restrict__ Wf,
                                                const float* __restrict__ bf,
                                                __half* __restrict__ K)
{
    int tid = blockIdx.x * 128 + threadIdx.x;
    const int XT = WW / 8;              // 80 thread-columns
    int x8 = tid % XT;
    int t2 = tid / XT;
    int y  = t2 % HH;
    int b  = t2 / HH;
    if (b >= BB) return;
    int x0 = x8 * 8;

    float acc[8][8];
#pragma unroll
    for (int o = 0; o < 8; ++o) {
        float bv = bf[o];
#pragma unroll
        for (int p = 0; p < 8; ++p) acc[o][p] = bv;
    }

    const float* kxb = kx + (size_t)b * CC * HWv + (size_t)y * WW + x0;
    const bool xm = (x0 > 0);
    const bool xp = (x0 + 8 < WW);

    for (int c = 0; c < CC; ++c) {
        const float* pl = kxb + (size_t)c * HWv;
#pragma unroll
        for (int r = 0; r < 3; ++r) {
            const int dy = r - 1;
            const bool rowok = (y + dy >= 0) && (y + dy < HH);
            const float* rp = pl + dy * WW;
            float row[10];
            if (rowok) {
                float4 v0 = *reinterpret_cast<const float4*>(rp);
                float4 v1 = *reinterpret_cast<const float4*>(rp + 4);
                row[0] = xm ? rp[-1] : 0.f;
                row[1] = v0.x; row[2] = v0.y; row[3] = v0.z; row[4] = v0.w;
                row[5] = v1.x; row[6] = v1.y; row[7] = v1.z; row[8] = v1.w;
                row[9] = xp ? rp[8] : 0.f;
            } else {
#pragma unroll
                for (int q = 0; q < 10; ++q) row[q] = 0.f;
            }
#pragma unroll
            for (int o = 0; o < 8; ++o) {
#pragma unroll
                for (int t = 0; t < 3; ++t) {
                    // wave-uniform index -> s_load -> SGPR operand in v_fma
                    float wv = Wf[((o * CC + c) * 3 + r) * 3 + t];
#pragma unroll
                    for (int p = 0; p < 8; ++p) acc[o][p] += wv * row[p + t];
                }
            }
        }
    }

    // normalization: a = aff / sum|aff|; K0 = 1 - sum(a)
    float k0[8];
#pragma unroll
    for (int p = 0; p < 8; ++p) {
        float asum = 0.f;
#pragma unroll
        for (int o = 0; o < 8; ++o) asum += fabsf(acc[o][p]);
        float rinv = 1.0f / asum;
        float s = 0.f;
#pragma unroll
        for (int o = 0; o < 8; ++o) { acc[o][p] *= rinv; s += acc[o][p]; }
        k0[p] = 1.0f - s;
    }

    size_t base = (size_t)b * 9 * HWv + (size_t)y * WW + x0;
    {
        H8 u;
#pragma unroll
        for (int p = 0; p < 8; ++p) u.h[p] = __float2half(k0[p]);
        *reinterpret_cast<float4*>(K + base) = u.f4;
    }
#pragma unroll
    for (int o = 0; o < 8; ++o) {
        H8 u;
#pragma unroll
        for (int p = 0; p < 8; ++p) u.h[p] = __float2half(acc[o][p]);
        *reinterpret_cast<float4*>(K + base + (size_t)(o + 1) * HWv) = u.f4;
    }
}

// ---------------------------------------------------------------------------
// Kernel 2: TWO fused propagation iterations, K held in registers.
// Tile: 16x64 interior (exact partition), staged x region 20x68 in LDS
// (row stride 73 -> <=2-way bank conflicts = free), step-1 result 18x66 in
// LDS. Each thread owns 4 px: loads their K (9x short4) ONCE, uses it for
// both steps. Step-1 halo ring (164 px) computed by threads 0..163 with
// on-demand K reads. Out-of-image semantics: staged x is zeroed outside,
// halo results masked to 0 (zero padding), interior always in-image.
// Tap map (OFFSETS order, proven R1):
//   out(r,c) = k0*x[r,c] + k1*x[r,c-1] + k2*x[r,c+1]
//            + k3*x[r-1,c] + k4*x[r-1,c-1] + k5*x[r-1,c+1]
//            + k6*x[r+1,c] + k7*x[r+1,c-1] + k8*x[r+1,c+1]
// ---------------------------------------------------------------------------
#define P2R 16
#define P2C 64
#define XSTR 73

__global__ __launch_bounds__(256) void prop2(const float* __restrict__ xin,
                                             const __half* __restrict__ Kk,
                                             float* __restrict__ xout)
{
    __shared__ float x0s[20 * XSTR];    // 5840 B
    __shared__ float x1s[18 * XSTR];    // 5256 B

    const int t  = threadIdx.x;
    const int tx = t & 15;              // 4-px col group
    const int ty = t >> 4;              // row 0..15

    int blk = blockIdx.x;
    const int xt = blk % (WW / P2C); blk /= (WW / P2C);
    const int yt = blk % (HH / P2R);
    const int b  = blk / (HH / P2R);
    const int y0  = yt * P2R;
    const int xg0 = xt * P2C;

    const float*  xb = xin + (size_t)b * HWv;
    const __half* Kb = Kk  + (size_t)b * 9 * HWv;

    // ---- stage x0: rows y0-2..y0+17, cols xg0-2..xg0+65 (zero outside) ----
#pragma unroll
    for (int pass = 0; pass < 6; ++pass) {
        int u = pass * 256 + t;
        if (u < 20 * 68) {
            int r = u / 68, c = u - (u / 68) * 68;
            int gy = y0 - 2 + r, gx = xg0 - 2 + c;
            bool ok = (gy >= 0 && gy < HH && gx >= 0 && gx < WW);
            x0s[r * XSTR + c] = ok ? xb[(size_t)gy * WW + gx] : 0.f;
        }
    }

    // ---- own-pixel K into registers (used by BOTH steps) ----
    float kv[9][4];
    {
        const __half* kp = Kb + (size_t)(y0 + ty) * WW + xg0 + 4 * tx;
#pragma unroll
        for (int k = 0; k < 9; ++k) {
            H4 u;
            u.s = *reinterpret_cast<const short4*>(kp + (size_t)k * HWv);
#pragma unroll
            for (int p = 0; p < 4; ++p) kv[k][p] = __half2float(u.h[p]);
        }
    }
    __syncthreads();

#define X0(r, c) x0s[((r) + 2) * XSTR + ((c) + 2)]
#define X1(r, c) x1s[((r) + 1) * XSTR + ((c) + 1)]

    // ---- step 1: own 4 interior px ----
#pragma unroll
    for (int p = 0; p < 4; ++p) {
        int c = 4 * tx + p, r = ty;
        float v = kv[0][p] * X0(r, c)
                + kv[1][p] * X0(r, c - 1)
                + kv[2][p] * X0(r, c + 1)
                + kv[3][p] * X0(r - 1, c)
                + kv[4][p] * X0(r - 1, c - 1)
                + kv[5][p] * X0(r - 1, c + 1)
                + kv[6][p] * X0(r + 1, c)
                + kv[7][p] * X0(r + 1, c - 1)
                + kv[8][p] * X0(r + 1, c + 1);
        X1(r, c) = v;
    }

    // ---- step 1: halo ring (164 px), threads 0..163, 1 px each ----
    if (t < 164) {
        int hr, hc;
        if      (t <  66) { hr = -1;      hc = t - 1;   }
        else if (t < 132) { hr = 16;      hc = t - 67;  }
        else if (t < 148) { hr = t - 132; hc = -1;      }
        else              { hr = t - 148; hc = 64;      }
        int gy = y0 + hr, gx = xg0 + hc;
        bool in = (gy >= 0 && gy < HH && gx >= 0 && gx < WW);
        int gyc = gy < 0 ? 0 : (gy > HH - 1 ? HH - 1 : gy);
        int gxc = gx < 0 ? 0 : (gx > WW - 1 ? WW - 1 : gx);
        const __half* kp = Kb + (size_t)gyc * WW + gxc;
        float hk[9];
#pragma unroll
        for (int k = 0; k < 9; ++k) hk[k] = __half2float(kp[(size_t)k * HWv]);
        float v = hk[0] * X0(hr, hc)
                + hk[1] * X0(hr, hc - 1)
                + hk[2] * X0(hr, hc + 1)
                + hk[3] * X0(hr - 1, hc)
                + hk[4] * X0(hr - 1, hc - 1)
                + hk[5] * X0(hr - 1, hc + 1)
                + hk[6] * X0(hr + 1, hc)
                + hk[7] * X0(hr + 1, hc - 1)
                + hk[8] * X0(hr + 1, hc + 1);
        X1(hr, hc) = in ? v : 0.f;
    }
    __syncthreads();

    // ---- step 2: own 4 px from x1, write global ----
    float o4[4];
#pragma unroll
    for (int p = 0; p < 4; ++p) {
        int c = 4 * tx + p, r = ty;
        o4[p] = kv[0][p] * X1(r, c)
              + kv[1][p] * X1(r, c - 1)
              + kv[2][p] * X1(r, c + 1)
              + kv[3][p] * X1(r - 1, c)
              + kv[4][p] * X1(r - 1, c - 1)
              + kv[5][p] * X1(r - 1, c + 1)
              + kv[6][p] * X1(r + 1, c)
              + kv[7][p] * X1(r + 1, c - 1)
              + kv[8][p] * X1(r + 1, c + 1);
    }
    *reinterpret_cast<float4*>(xout + (size_t)b * HWv
                               + (size_t)(y0 + ty) * WW + xg0 + 4 * tx) =
        make_float4(o4[0], o4[1], o4[2], o4[3]);
#undef X0
#undef X1
}

// ---------------------------------------------------------------------------
extern "C" void kernel_launch(void* const* d_in, const int* in_sizes, int n_in,
                              void* d_out, int out_size, void* d_ws, size_t ws_size,
                              hipStream_t stream) {
    const float* kx   = (const float*)d_in[0];   // [4,32,480,640]
    const float* x_in = (const float*)d_in[1];   // [4,1,480,640]
    const float* Wf   = (const float*)d_in[2];   // [8,32,3,3]
    const float* bf   = (const float*)d_in[3];   // [8]
    float* out  = (float*)d_out;                 // [4,1,480,640]

    __half* Kbuf = (__half*)d_ws;                               // 22.1 MB fp16
    float*  xbuf = (float*)((char*)d_ws +
                            (size_t)9 * BB * HWv * sizeof(__half));  // 4.9 MB

    // conv: 8 px/thread, block=128 -> 1200 blocks (R9 structure, 108 us)
    const int cthreads = BB * HH * (WW / 8);      // 153600
    conv_gen<<<cthreads / 128, 128, 0, stream>>>(kx, Wf, bf, Kbuf);

    // prop: 6 launches x 2 fused iterations, 1200 blocks x 256 threads
    const int pblocks = BB * (HH / P2R) * (WW / P2C);   // 1200
    const float* src = x_in;
    for (int l = 0; l < 6; ++l) {
        float* dst = (l % 2 == 0) ? xbuf : out;   // l=5 (odd) -> d_out final
        prop2<<<pblocks, 256, 0, stream>>>(src, Kbuf, dst);
        src = dst;
    }
}